// Round 1
// baseline (144.226 us; speedup 1.0000x reference)
//
#include <hip/hip_runtime.h>
#include <hip/hip_fp16.h>
#include <math.h>

// WaveNet collapsed to the last time column (symmetric pad (K-1)*d puts the
// k=1 tap of every dilated conv in the zero pad at the final position).
// Flag-free 3-kernel pipeline (R5/R7 measured: ANY cross-block flag spin is
// worse than a kernel boundary on MI355X).
// Algebraic fold: c_{l+1} = (Wr_l+I) z_l  =>  M_{f,g}[l] = W_{f,g}[l](Wr_{l-1}+I),
// so the serial chain is z' = tanh(M_f z) * sigmoid(M_g z): ONE LDS round-trip
// and 2 fp16 dot2 dots per layer (res matvec moved into parallel precompute).
//   K1: grid(41,2): 80 fold blocks (32x32x32 matmul -> fp16 blob) + prep
//       block (start conv -> c0).
//   K2: 8 blocks x 1 wave (one CU per batch): 40-layer recurrence,
//       4-deep register prefetch, v_dot2_f32_f16 inner product.
//   K3: merged tail, 8 blocks (one per batch) x 256 threads: skip matvec
//       (fp32, z staged in LDS), relu, end1+end2, direct out[b] write.
//       No atomics / threadfence / cnt spin (replaces old k3a+k3b pair).

#define NL 40
#define TLEN 8192

// ws float-offset layout
#define F_BLOB 0        // fp16 [40][64 lanes][32 halfs] = 81920 halfs
#define F_C0   40960    // [8][32]
#define F_Z    41216    // [40][8][32] fp32 z for the skip matvec

typedef __attribute__((ext_vector_type(2))) _Float16 h2;

#if defined(__has_builtin)
#if __has_builtin(__builtin_amdgcn_fdot2)
#define HAS_FDOT2 1
#endif
#endif

__device__ __forceinline__ float FDOT2(h2 a, h2 b, float c) {
#ifdef HAS_FDOT2
    return __builtin_amdgcn_fdot2(a, b, c, false);
#else
    return c + (float)a.x * (float)b.x + (float)a.y * (float)b.y;
#endif
}

__device__ __forceinline__ float tanh_fast(float f) {
    f = fminf(fmaxf(f, -15.f), 15.f);
    float e2 = __expf(2.f * f);
    return (e2 - 1.f) / (e2 + 1.f);
}

// ------------------------------------------------- K1: fold weights + prep
__global__ __launch_bounds__(256) void k1_fold(
    const float* __restrict__ x, const float* __restrict__ start_w,
    const float* __restrict__ filter_w, const float* __restrict__ gate_w,
    const float* __restrict__ res_w, float* __restrict__ ws)
{
    const int l = blockIdx.x, m = blockIdx.y;   // m: 0=filter, 1=gate
    const int t = threadIdx.x;

    if (l == NL) {
        if (m == 0) {
            const int b = t >> 5, ch = t & 31;
            float acc = 0.f;
#pragma unroll
            for (int j = 0; j < 6; ++j)
                acc += start_w[ch * 6 + j] * x[(b * 6 + j) * TLEN + TLEN - 1];
            ws[F_C0 + t] = acc;
        }
        return;
    }

    __shared__ float F[32][32];
    __shared__ __align__(16) float R[32][36];
    const float* src = m ? gate_w : filter_w;
    for (int e = t; e < 1024; e += 256)
        F[e >> 5][e & 31] = src[(l * 1024 + e) * 2];   // k=0 taps
    if (l > 0)
        for (int e = t; e < 1024; e += 256) {
            const int k = e >> 5, j = e & 31;
            R[k][j] = res_w[(l - 1) * 1024 + e] + (k == j ? 1.f : 0.f);
        }
    __syncthreads();

    const int ch = t >> 3, jg = t & 7, j0 = jg * 4;
    float o0, o1, o2, o3;
    if (l == 0) {
        o0 = F[ch][j0]; o1 = F[ch][j0+1]; o2 = F[ch][j0+2]; o3 = F[ch][j0+3];
    } else {
        o0 = o1 = o2 = o3 = 0.f;
#pragma unroll
        for (int k = 0; k < 32; ++k) {
            const float fv = F[ch][k];
            const float4 rv = *(const float4*)&R[k][j0];
            o0 += fv * rv.x; o1 += fv * rv.y; o2 += fv * rv.z; o3 += fv * rv.w;
        }
    }
    // blob: [l][lane=h*32+ch][ f:0..15 | g:16..31 ], pos = j0 & 15
    const int hh = jg >> 2;
    __half* dst = (__half*)ws + (size_t)l * 2048 + (hh * 32 + ch) * 32
                + (m ? 16 : 0) + (j0 & 15);
    ((__half2*)dst)[0] = __floats2half2_rn(o0, o1);
    ((__half2*)dst)[1] = __floats2half2_rn(o2, o3);
}

// ------------------------------------------------------------ K2: recurrence
#define K2_PREF(L, W) do {                                                   \
    if ((L) < NL) {                                                          \
        _Pragma("unroll")                                                    \
        for (int i = 0; i < 4; ++i)                                          \
            W[i] = blob[(L) * 256 + lane * 4 + i];                           \
    }                                                                        \
} while (0)

#define K2_STEP(L, W) do {                                                   \
    h2 s[8];                                                                 \
    { const float4* sp = (const float4*)zsm;                                 \
      *(float4*)&s[0] = sp[h * 2];                                           \
      *(float4*)&s[4] = sp[h * 2 + 1]; }                                     \
    float f = 0.f, g = 0.f;                                                  \
    const h2* wf = (const h2*)&W[0];                                         \
    const h2* wg = (const h2*)&W[2];                                         \
    _Pragma("unroll")                                                        \
    for (int i = 0; i < 8; ++i) {                                            \
        f = FDOT2(wf[i], s[i], f);                                           \
        g = FDOT2(wg[i], s[i], g);                                           \
    }                                                                        \
    f += __shfl_xor(f, 32, 64);                                              \
    g += __shfl_xor(g, 32, 64);                                              \
    float z = tanh_fast(f) * (1.f / (1.f + __expf(-g)));                     \
    if (h == 0) {                                                            \
        zbuf[((L) * 8 + b) * 32 + ch] = z;                                   \
        zsm[ch] = __float2half(z);                                           \
    }                                                                        \
    __builtin_amdgcn_wave_barrier();                                         \
    K2_PREF((L) + 4, W);                                                     \
} while (0)

__global__ __launch_bounds__(64) void k2_recur(float* __restrict__ ws)
{
    const int b = blockIdx.x;            // batch, one wave per CU
    const int lane = threadIdx.x;
    const int ch = lane & 31, h = lane >> 5;
    __shared__ __align__(16) __half zsm[32];
    float* zbuf = ws + F_Z;

    if (h == 0) zsm[ch] = __float2half(ws[F_C0 + b * 32 + ch]);
    __builtin_amdgcn_wave_barrier();

    const float4* blob = (const float4*)ws;
    float4 w0[4], w1[4], w2[4], w3[4];
    K2_PREF(0, w0); K2_PREF(1, w1); K2_PREF(2, w2); K2_PREF(3, w3);
    for (int l = 0; l < NL; l += 4) {
        K2_STEP(l + 0, w0);
        K2_STEP(l + 1, w1);
        K2_STEP(l + 2, w2);
        K2_STEP(l + 3, w3);
    }
}

// ----------------------------------------- K3: skip matvec + end1 + end2
// One block per batch. z[b] staged in LDS (broadcast reads -> no bank
// conflicts). skip row t = thread t; then end1 row t = thread t; block
// reduce with end2 weights; direct out[b] store. No atomics.
__global__ __launch_bounds__(256) void k3_tail(
    const float* __restrict__ skip_w,
    const float* __restrict__ end1_w, const float* __restrict__ end1_b,
    const float* __restrict__ end2_w, const float* __restrict__ end2_b,
    float* __restrict__ ws, float* __restrict__ out)
{
    const int b = blockIdx.x, t = threadIdx.x;
    __shared__ __align__(16) float zsm[NL * 32];   // 5 KB
    __shared__ __align__(16) float hsm[256];
    __shared__ float psum[4];

    // stage z for this batch: ws layout F_Z + (l*8 + b)*32 + ch
    for (int idx = t; idx < NL * 32; idx += 256) {
        const int l = idx >> 5, ch = idx & 31;
        zsm[idx] = ws[F_Z + (l * 8 + b) * 32 + ch];
    }
    __syncthreads();

    // skip_sum row t over all 40 layers (fp32, float4 vector loads)
    float acc = 0.f;
    const float4* z4 = (const float4*)zsm;
#pragma unroll 4
    for (int l = 0; l < NL; ++l) {
        const float4* w4 = (const float4*)(skip_w + (size_t)(l * 256 + t) * 32);
        const float4* zz = z4 + l * 8;
#pragma unroll
        for (int i = 0; i < 8; ++i) {
            float4 wv = w4[i], zv = zz[i];
            acc += wv.x*zv.x + wv.y*zv.y + wv.z*zv.z + wv.w*zv.w;
        }
    }
    hsm[t] = fmaxf(acc, 0.f);                      // relu(skip_sum)
    __syncthreads();

    // end1 row t + relu, then scale by end2_w[t] and block-reduce
    float e = 0.f;
    const float4* w1 = (const float4*)(end1_w + (size_t)t * 256);
    const float4* h4 = (const float4*)hsm;
#pragma unroll
    for (int i = 0; i < 64; ++i) {
        float4 wv = w1[i], hv = h4[i];
        e += wv.x*hv.x + wv.y*hv.y + wv.z*hv.z + wv.w*hv.w;
    }
    e = fmaxf(e + end1_b[t], 0.f);
    float pe = e * end2_w[t];
#pragma unroll
    for (int off = 32; off > 0; off >>= 1)
        pe += __shfl_down(pe, off, 64);
    if ((t & 63) == 0) psum[t >> 6] = pe;
    __syncthreads();
    if (t == 0)
        out[b] = psum[0] + psum[1] + psum[2] + psum[3] + end2_b[0];
}

extern "C" void kernel_launch(void* const* d_in, const int* in_sizes, int n_in,
                              void* d_out, int out_size, void* d_ws, size_t ws_size,
                              hipStream_t stream) {
    const float* x        = (const float*)d_in[0];
    const float* start_w  = (const float*)d_in[1];
    const float* filter_w = (const float*)d_in[2];
    const float* gate_w   = (const float*)d_in[3];
    const float* res_w    = (const float*)d_in[4];
    const float* skip_w   = (const float*)d_in[5];
    const float* end1_w   = (const float*)d_in[6];
    const float* end1_b   = (const float*)d_in[7];
    const float* end2_w   = (const float*)d_in[8];
    const float* end2_b   = (const float*)d_in[9];
    float* out = (float*)d_out;
    float* ws  = (float*)d_ws;

    k1_fold <<<dim3(NL + 1, 2), 256, 0, stream>>>(x, start_w, filter_w,
                                                  gate_w, res_w, ws);
    k2_recur<<<8, 64, 0, stream>>>(ws);
    k3_tail <<<8, 256, 0, stream>>>(skip_w, end1_w, end1_b, end2_w, end2_b,
                                    ws, out);
}

// Round 2
// 124.639 us; speedup vs baseline: 1.1572x; 1.1572x over previous
//
#include <hip/hip_runtime.h>
#include <hip/hip_fp16.h>
#include <math.h>

// WaveNet collapsed to the last time column (symmetric pad (K-1)*d puts the
// k=1 tap of every dilated conv in the zero pad at the final position).
// 2-kernel pipeline:
//   K1: grid(41,2): 80 fold blocks (32x32x32 matmul -> fp16 blob) + prep
//       block (start conv -> c0).
//   K2_fused: 8 blocks x 5 waves (one block per batch):
//     wave 0:   40-layer serial recurrence (4-deep register prefetch,
//               v_dot2_f32_f16), publishes z[l] to LDS zhist + LDS progress
//               counter (intra-block producer-consumer; NO cross-block spin,
//               which R5/R7 measured as worse than a kernel boundary).
//     waves1-4: 256 threads = 256 skip rows; double-buffered register
//               prefetch of skip_w layer l+1 while waiting for z[l] ->
//               the whole 1.25 MB/block skip stream hides under the chain.
//               After the chain: relu, end1+end2, direct out[b] write.
// R1 post-mortem baked in: the tail must either be 300-block wide (old k3a)
// or hidden under the serial chain; an 8-block standalone tail is 60 us of
// latency-bound streaming.
// Algebraic fold: c_{l+1} = (Wr_l+I) z_l  =>  M_{f,g}[l] = W_{f,g}[l](Wr_{l-1}+I),
// so the serial chain is z' = tanh(M_f z) * sigmoid(M_g z).

#define NL 40
#define TLEN 8192

// ws float-offset layout
#define F_BLOB 0        // fp16 [40][64 lanes][32 halfs] = 81920 halfs
#define F_C0   40960    // [8][32]

typedef __attribute__((ext_vector_type(2))) _Float16 h2;

#if defined(__has_builtin)
#if __has_builtin(__builtin_amdgcn_fdot2)
#define HAS_FDOT2 1
#endif
#endif

__device__ __forceinline__ float FDOT2(h2 a, h2 b, float c) {
#ifdef HAS_FDOT2
    return __builtin_amdgcn_fdot2(a, b, c, false);
#else
    return c + (float)a.x * (float)b.x + (float)a.y * (float)b.y;
#endif
}

__device__ __forceinline__ float tanh_fast(float f) {
    f = fminf(fmaxf(f, -15.f), 15.f);
    float e2 = __expf(2.f * f);
    return (e2 - 1.f) / (e2 + 1.f);
}

// ------------------------------------------------- K1: fold weights + prep
__global__ __launch_bounds__(256) void k1_fold(
    const float* __restrict__ x, const float* __restrict__ start_w,
    const float* __restrict__ filter_w, const float* __restrict__ gate_w,
    const float* __restrict__ res_w, float* __restrict__ ws)
{
    const int l = blockIdx.x, m = blockIdx.y;   // m: 0=filter, 1=gate
    const int t = threadIdx.x;

    if (l == NL) {
        if (m == 0) {
            const int b = t >> 5, ch = t & 31;
            float acc = 0.f;
#pragma unroll
            for (int j = 0; j < 6; ++j)
                acc += start_w[ch * 6 + j] * x[(b * 6 + j) * TLEN + TLEN - 1];
            ws[F_C0 + t] = acc;
        }
        return;
    }

    __shared__ float F[32][32];
    __shared__ __align__(16) float R[32][36];
    const float* src = m ? gate_w : filter_w;
    for (int e = t; e < 1024; e += 256)
        F[e >> 5][e & 31] = src[(l * 1024 + e) * 2];   // k=0 taps
    if (l > 0)
        for (int e = t; e < 1024; e += 256) {
            const int k = e >> 5, j = e & 31;
            R[k][j] = res_w[(l - 1) * 1024 + e] + (k == j ? 1.f : 0.f);
        }
    __syncthreads();

    const int ch = t >> 3, jg = t & 7, j0 = jg * 4;
    float o0, o1, o2, o3;
    if (l == 0) {
        o0 = F[ch][j0]; o1 = F[ch][j0+1]; o2 = F[ch][j0+2]; o3 = F[ch][j0+3];
    } else {
        o0 = o1 = o2 = o3 = 0.f;
#pragma unroll
        for (int k = 0; k < 32; ++k) {
            const float fv = F[ch][k];
            const float4 rv = *(const float4*)&R[k][j0];
            o0 += fv * rv.x; o1 += fv * rv.y; o2 += fv * rv.z; o3 += fv * rv.w;
        }
    }
    // blob: [l][lane=h*32+ch][ f:0..15 | g:16..31 ], pos = j0 & 15
    const int hh = jg >> 2;
    __half* dst = (__half*)ws + (size_t)l * 2048 + (hh * 32 + ch) * 32
                + (m ? 16 : 0) + (j0 & 15);
    ((__half2*)dst)[0] = __floats2half2_rn(o0, o1);
    ((__half2*)dst)[1] = __floats2half2_rn(o2, o3);
}

// --------------------------------------- K2: recurrence + hidden skip tail
#define K2_PREF(L, W) do {                                                   \
    if ((L) < NL) {                                                          \
        _Pragma("unroll")                                                    \
        for (int i = 0; i < 4; ++i)                                          \
            W[i] = blob[(L) * 256 + lane * 4 + i];                           \
    }                                                                        \
} while (0)

#define K2_STEP(L, W) do {                                                   \
    h2 sv[8];                                                                \
    { const float4* sp = (const float4*)zsm;                                 \
      *(float4*)&sv[0] = sp[h * 2];                                          \
      *(float4*)&sv[4] = sp[h * 2 + 1]; }                                    \
    float f = 0.f, g = 0.f;                                                  \
    const h2* wf = (const h2*)&W[0];                                         \
    const h2* wg = (const h2*)&W[2];                                         \
    _Pragma("unroll")                                                        \
    for (int i = 0; i < 8; ++i) {                                            \
        f = FDOT2(wf[i], sv[i], f);                                          \
        g = FDOT2(wg[i], sv[i], g);                                          \
    }                                                                        \
    f += __shfl_xor(f, 32, 64);                                              \
    g += __shfl_xor(g, 32, 64);                                              \
    float z = tanh_fast(f) * (1.f / (1.f + __expf(-g)));                     \
    if (h == 0) {                                                            \
        zhist[(L) * 32 + ch] = z;                                            \
        zsm[ch] = __float2half(z);                                           \
    }                                                                        \
    __threadfence_block();      /* lgkmcnt(0): zhist visible before prog */  \
    if (lane == 0) *(volatile int*)&prog = (L) + 1;                          \
    __builtin_amdgcn_wave_barrier();                                         \
    K2_PREF((L) + 4, W);                                                     \
} while (0)

// consumer-side macros (s = skip row 0..255)
#define LOADW(W, L) do {                                                     \
    const float4* wp_ = (const float4*)(skip_w + ((size_t)(L) * 256 + s) * 32);\
    _Pragma("unroll")                                                        \
    for (int i_ = 0; i_ < 8; ++i_) W[i_] = wp_[i_];                          \
} while (0)

#define WAITP(L) do {                                                        \
    while (*(volatile int*)&prog <= (L)) {}                                  \
    __threadfence_block();                                                   \
} while (0)

#define ACCUM(W, L) do {                                                     \
    const float4* z4_ = (const float4*)(zhist + (L) * 32);                   \
    _Pragma("unroll")                                                        \
    for (int i_ = 0; i_ < 8; ++i_) {                                         \
        float4 zv_ = z4_[i_];                                                \
        acc += W[i_].x*zv_.x + W[i_].y*zv_.y                                 \
             + W[i_].z*zv_.z + W[i_].w*zv_.w;                                \
    }                                                                        \
} while (0)

__global__ __launch_bounds__(320) void k2_fused(
    const float* __restrict__ skip_w,
    const float* __restrict__ end1_w, const float* __restrict__ end1_b,
    const float* __restrict__ end2_w, const float* __restrict__ end2_b,
    float* __restrict__ ws, float* __restrict__ out)
{
    const int b = blockIdx.x, t = threadIdx.x;
    __shared__ __align__(16) __half zsm[32];
    __shared__ __align__(16) float zhist[NL * 32];   // 5 KB
    __shared__ __align__(16) float hsm[256];
    __shared__ float psum[5];
    __shared__ int prog;

    if (t == 0) prog = 0;
    __syncthreads();

    if (t < 64) {
        // ------------- producer wave: the 40-layer serial recurrence
        const int lane = t, ch = lane & 31, h = lane >> 5;
        if (h == 0) zsm[ch] = __float2half(ws[F_C0 + b * 32 + ch]);
        __builtin_amdgcn_wave_barrier();

        const float4* blob = (const float4*)ws;
        float4 w0[4], w1[4], w2[4], w3[4];
        K2_PREF(0, w0); K2_PREF(1, w1); K2_PREF(2, w2); K2_PREF(3, w3);
        for (int l = 0; l < NL; l += 4) {
            K2_STEP(l + 0, w0);
            K2_STEP(l + 1, w1);
            K2_STEP(l + 2, w2);
            K2_STEP(l + 3, w3);
        }
    } else {
        // ------------- consumer waves: skip matvec hidden under the chain
        const int s = t - 64;                       // 0..255 = skip row
        float acc = 0.f;
        float4 wa[8], wb[8];                        // double-buffered weights
        LOADW(wa, 0);
        for (int l = 0; l < NL; l += 2) {
            LOADW(wb, l + 1);                       // prefetch (z-independent)
            WAITP(l);
            ACCUM(wa, l);
            if (l + 2 < NL) LOADW(wa, l + 2);
            WAITP(l + 1);
            ACCUM(wb, l + 1);
        }
        hsm[s] = fmaxf(acc, 0.f);                   // relu(skip_sum)
    }
    __syncthreads();

    // ------------- end1 + end2 (threads 64..319 own the 256 rows)
    float pe = 0.f;
    if (t >= 64) {
        const int s = t - 64;
        float e = 0.f;
        const float4* w1p = (const float4*)(end1_w + (size_t)s * 256);
        const float4* h4 = (const float4*)hsm;
#pragma unroll
        for (int i = 0; i < 64; ++i) {
            float4 wv = w1p[i], hv = h4[i];
            e += wv.x*hv.x + wv.y*hv.y + wv.z*hv.z + wv.w*hv.w;
        }
        e = fmaxf(e + end1_b[s], 0.f);
        pe = e * end2_w[s];
    }
#pragma unroll
    for (int off = 32; off > 0; off >>= 1)
        pe += __shfl_down(pe, off, 64);
    if ((t & 63) == 0) psum[t >> 6] = pe;
    __syncthreads();
    if (t == 0)
        out[b] = psum[1] + psum[2] + psum[3] + psum[4] + end2_b[0];
}

extern "C" void kernel_launch(void* const* d_in, const int* in_sizes, int n_in,
                              void* d_out, int out_size, void* d_ws, size_t ws_size,
                              hipStream_t stream) {
    const float* x        = (const float*)d_in[0];
    const float* start_w  = (const float*)d_in[1];
    const float* filter_w = (const float*)d_in[2];
    const float* gate_w   = (const float*)d_in[3];
    const float* res_w    = (const float*)d_in[4];
    const float* skip_w   = (const float*)d_in[5];
    const float* end1_w   = (const float*)d_in[6];
    const float* end1_b   = (const float*)d_in[7];
    const float* end2_w   = (const float*)d_in[8];
    const float* end2_b   = (const float*)d_in[9];
    float* out = (float*)d_out;
    float* ws  = (float*)d_ws;

    k1_fold <<<dim3(NL + 1, 2), 256, 0, stream>>>(x, start_w, filter_w,
                                                  gate_w, res_w, ws);
    k2_fused<<<8, 320, 0, stream>>>(skip_w, end1_w, end1_b, end2_w, end2_b,
                                    ws, out);
}

// Round 3
// 120.249 us; speedup vs baseline: 1.1994x; 1.0365x over previous
//
#include <hip/hip_runtime.h>
#include <hip/hip_fp16.h>
#include <math.h>

// WaveNet collapsed to the last time column (symmetric pad (K-1)*d puts the
// k=1 tap of every dilated conv in the zero pad at the final position).
// 3-kernel pipeline:
//   K1: grid(41,2): 80 fold blocks (32x32x32 matmul -> fp16 blob) + prep
//       block (start conv -> c0, zero obuf/cnt).
//   K2_fused: 8 blocks x 5 waves (one block per batch):
//     wave 0:   40-layer serial recurrence (4-deep register prefetch,
//               v_dot2_f32_f16). Publishes z[l] to LDS zhist, then
//               s_waitcnt lgkmcnt(0) (LDS-ONLY fence - R2 post-mortem:
//               __threadfence_block's vmcnt(0) drain was the 51us bug),
//               then LDS progress counter.
//     waves1-4: 256 threads = 256 skip rows; double-buffered register
//               prefetch of skip_w; spin on LDS prog (HW branch dependency
//               orders the zhist reads; no vmcnt drain in the loop) ->
//               the whole 1.25 MB/block skip stream hides under the chain.
//               relu(skip_sum) written straight to global F_H (one owner
//               per element, no atomics). Replaces old k3a.
//   K3b: end1+end2 exactly as the proven 98.5us baseline (4x8 blocks,
//        register-prefetched end1 rows, atomic-cnt finish).
// R1 lesson: tail must be wide OR hidden under the chain - never 8-block
// standalone. R2 lesson: never put a vmcnt-draining fence in a pipelined
// loop.
// Algebraic fold: c_{l+1} = (Wr_l+I) z_l  =>  M_{f,g}[l] = W_{f,g}[l](Wr_{l-1}+I),
// so the serial chain is z' = tanh(M_f z) * sigmoid(M_g z).

#define NL 40
#define TLEN 8192

// ws float-offset layout (kept from baseline; F_Z region now unused)
#define F_BLOB 0        // fp16 [40][64 lanes][32 halfs] = 81920 halfs
#define F_C0   40960    // [8][32]
#define F_H    51456    // [8][256] relu(skip_sum)
#define F_OB   53504    // [8]
#define F_CNT  53512    // [8] ints

typedef __attribute__((ext_vector_type(2))) _Float16 h2;

#if defined(__has_builtin)
#if __has_builtin(__builtin_amdgcn_fdot2)
#define HAS_FDOT2 1
#endif
#endif

__device__ __forceinline__ float FDOT2(h2 a, h2 b, float c) {
#ifdef HAS_FDOT2
    return __builtin_amdgcn_fdot2(a, b, c, false);
#else
    return c + (float)a.x * (float)b.x + (float)a.y * (float)b.y;
#endif
}

__device__ __forceinline__ float tanh_fast(float f) {
    f = fminf(fmaxf(f, -15.f), 15.f);
    float e2 = __expf(2.f * f);
    return (e2 - 1.f) / (e2 + 1.f);
}

// ------------------------------------------------- K1: fold weights + prep
__global__ __launch_bounds__(256) void k1_fold(
    const float* __restrict__ x, const float* __restrict__ start_w,
    const float* __restrict__ filter_w, const float* __restrict__ gate_w,
    const float* __restrict__ res_w, float* __restrict__ ws)
{
    const int l = blockIdx.x, m = blockIdx.y;   // m: 0=filter, 1=gate
    const int t = threadIdx.x;

    if (l == NL) {
        if (m == 0) {
            const int b = t >> 5, ch = t & 31;
            float acc = 0.f;
#pragma unroll
            for (int j = 0; j < 6; ++j)
                acc += start_w[ch * 6 + j] * x[(b * 6 + j) * TLEN + TLEN - 1];
            ws[F_C0 + t] = acc;
            if (t < 8) { ws[F_OB + t] = 0.f; ((int*)(ws + F_CNT))[t] = 0; }
        }
        return;
    }

    __shared__ float F[32][32];
    __shared__ __align__(16) float R[32][36];
    const float* src = m ? gate_w : filter_w;
    for (int e = t; e < 1024; e += 256)
        F[e >> 5][e & 31] = src[(l * 1024 + e) * 2];   // k=0 taps
    if (l > 0)
        for (int e = t; e < 1024; e += 256) {
            const int k = e >> 5, j = e & 31;
            R[k][j] = res_w[(l - 1) * 1024 + e] + (k == j ? 1.f : 0.f);
        }
    __syncthreads();

    const int ch = t >> 3, jg = t & 7, j0 = jg * 4;
    float o0, o1, o2, o3;
    if (l == 0) {
        o0 = F[ch][j0]; o1 = F[ch][j0+1]; o2 = F[ch][j0+2]; o3 = F[ch][j0+3];
    } else {
        o0 = o1 = o2 = o3 = 0.f;
#pragma unroll
        for (int k = 0; k < 32; ++k) {
            const float fv = F[ch][k];
            const float4 rv = *(const float4*)&R[k][j0];
            o0 += fv * rv.x; o1 += fv * rv.y; o2 += fv * rv.z; o3 += fv * rv.w;
        }
    }
    // blob: [l][lane=h*32+ch][ f:0..15 | g:16..31 ], pos = j0 & 15
    const int hh = jg >> 2;
    __half* dst = (__half*)ws + (size_t)l * 2048 + (hh * 32 + ch) * 32
                + (m ? 16 : 0) + (j0 & 15);
    ((__half2*)dst)[0] = __floats2half2_rn(o0, o1);
    ((__half2*)dst)[1] = __floats2half2_rn(o2, o3);
}

// --------------------------------------- K2: recurrence + hidden skip tail
#define K2_PREF(L, W) do {                                                   \
    if ((L) < NL) {                                                          \
        _Pragma("unroll")                                                    \
        for (int i = 0; i < 4; ++i)                                          \
            W[i] = blob[(L) * 256 + lane * 4 + i];                           \
    }                                                                        \
} while (0)

#define K2_STEP(L, W) do {                                                   \
    h2 sv[8];                                                                \
    { const float4* sp = (const float4*)zsm;                                 \
      *(float4*)&sv[0] = sp[h * 2];                                          \
      *(float4*)&sv[4] = sp[h * 2 + 1]; }                                    \
    float f = 0.f, g = 0.f;                                                  \
    const h2* wf = (const h2*)&W[0];                                         \
    const h2* wg = (const h2*)&W[2];                                         \
    _Pragma("unroll")                                                        \
    for (int i = 0; i < 8; ++i) {                                            \
        f = FDOT2(wf[i], sv[i], f);                                          \
        g = FDOT2(wg[i], sv[i], g);                                          \
    }                                                                        \
    f += __shfl_xor(f, 32, 64);                                              \
    g += __shfl_xor(g, 32, 64);                                              \
    float z = tanh_fast(f) * (1.f / (1.f + __expf(-g)));                     \
    if (h == 0) {                                                            \
        zhist[(L) * 32 + ch] = z;                                            \
        zsm[ch] = __float2half(z);                                           \
    }                                                                        \
    /* LDS-only release fence: zhist/zsm visible before prog bump. */        \
    asm volatile("s_waitcnt lgkmcnt(0)" ::: "memory");                       \
    if (lane == 0) *(volatile int*)&prog = (L) + 1;                          \
    __builtin_amdgcn_wave_barrier();                                         \
    K2_PREF((L) + 4, W);                                                     \
} while (0)

// consumer-side macros (s = skip row 0..255)
#define LOADW(W, L) do {                                                     \
    const float4* wp_ = (const float4*)(skip_w + ((size_t)(L) * 256 + s) * 32);\
    _Pragma("unroll")                                                        \
    for (int i_ = 0; i_ < 8; ++i_) W[i_] = wp_[i_];                          \
} while (0)

// acquire: HW orders the zhist reads behind the spin's branch dependency;
// the empty asm only stops COMPILER hoisting. No vmcnt drain (R2 bug).
#define WAITP(L) do {                                                        \
    while (*(volatile int*)&prog <= (L)) {}                                  \
    asm volatile("" ::: "memory");                                           \
} while (0)

#define ACCUM(W, L) do {                                                     \
    const float4* z4_ = (const float4*)(zhist + (L) * 32);                   \
    _Pragma("unroll")                                                        \
    for (int i_ = 0; i_ < 8; ++i_) {                                         \
        float4 zv_ = z4_[i_];                                                \
        acc += W[i_].x*zv_.x + W[i_].y*zv_.y                                 \
             + W[i_].z*zv_.z + W[i_].w*zv_.w;                                \
    }                                                                        \
} while (0)

__global__ __launch_bounds__(320) void k2_fused(
    const float* __restrict__ skip_w, float* __restrict__ ws)
{
    const int b = blockIdx.x, t = threadIdx.x;
    __shared__ __align__(16) __half zsm[32];
    __shared__ __align__(16) float zhist[NL * 32];   // 5 KB
    __shared__ int prog;

    if (t == 0) prog = 0;
    __syncthreads();

    if (t < 64) {
        // ------------- producer wave: the 40-layer serial recurrence
        const int lane = t, ch = lane & 31, h = lane >> 5;
        if (h == 0) zsm[ch] = __float2half(ws[F_C0 + b * 32 + ch]);
        __builtin_amdgcn_wave_barrier();

        const float4* blob = (const float4*)ws;
        float4 w0[4], w1[4], w2[4], w3[4];
        K2_PREF(0, w0); K2_PREF(1, w1); K2_PREF(2, w2); K2_PREF(3, w3);
        for (int l = 0; l < NL; l += 4) {
            K2_STEP(l + 0, w0);
            K2_STEP(l + 1, w1);
            K2_STEP(l + 2, w2);
            K2_STEP(l + 3, w3);
        }
    } else {
        // ------------- consumer waves: skip matvec hidden under the chain
        const int s = t - 64;                       // 0..255 = skip row
        float acc = 0.f;
        float4 wa[8], wb[8];                        // double-buffered weights
        LOADW(wa, 0);
        for (int l = 0; l < NL; l += 2) {
            LOADW(wb, l + 1);                       // prefetch (z-independent)
            WAITP(l);
            ACCUM(wa, l);
            if (l + 2 < NL) LOADW(wa, l + 2);
            WAITP(l + 1);
            ACCUM(wb, l + 1);
        }
        // relu(skip_sum) -> global, one owner per element, no atomics
        ws[F_H + b * 256 + s] = fmaxf(acc, 0.f);
    }
}

// --------------------------------------------------- K3b: end1 + end2 + out
__global__ __launch_bounds__(256) void k3b_end(
    const float* __restrict__ end1_w, const float* __restrict__ end1_b,
    const float* __restrict__ end2_w, const float* __restrict__ end2_b,
    float* __restrict__ ws, float* __restrict__ out)
{
    const int q = blockIdx.x, b = blockIdx.y, t = threadIdx.x;
    __shared__ __align__(16) float hsm[256];
    __shared__ float psum[64][5];
    const int p = t >> 6, oc = t & 63, row = q * 64 + oc;

    float4 wreg[16];
    const float4* wp = (const float4*)(end1_w + (size_t)row * 256 + p * 64);
#pragma unroll
    for (int i = 0; i < 16; ++i) wreg[i] = wp[i];

    hsm[t] = ws[F_H + b * 256 + t];               // already relu'd
    __syncthreads();
    const float4* h4 = (const float4*)(hsm + p * 64);
    float acc = 0.f;
#pragma unroll
    for (int i = 0; i < 16; ++i) {
        float4 wv = wreg[i], hv = h4[i];
        acc += wv.x*hv.x + wv.y*hv.y + wv.z*hv.z + wv.w*hv.w;
    }
    psum[oc][p] = acc;
    __syncthreads();
    if (t < 64) {
        const int rr = q * 64 + t;
        float e = psum[t][0] + psum[t][1] + psum[t][2] + psum[t][3]
                + end1_b[rr];
        e = fmaxf(e, 0.f);
        float pe = e * end2_w[rr];
#pragma unroll
        for (int off = 32; off > 0; off >>= 1)
            pe += __shfl_down(pe, off, 64);
        if (t == 0) {
            float* obuf = ws + F_OB;
            int* cnt = (int*)(ws + F_CNT);
            atomicAdd(&obuf[b], pe);
            __threadfence();
            int old = __hip_atomic_fetch_add(&cnt[b], 1, __ATOMIC_ACQ_REL,
                                             __HIP_MEMORY_SCOPE_AGENT);
            if (old == 3) {
                float tot = __hip_atomic_load(&obuf[b], __ATOMIC_ACQUIRE,
                                              __HIP_MEMORY_SCOPE_AGENT);
                out[b] = tot + end2_b[0];
            }
        }
    }
}

extern "C" void kernel_launch(void* const* d_in, const int* in_sizes, int n_in,
                              void* d_out, int out_size, void* d_ws, size_t ws_size,
                              hipStream_t stream) {
    const float* x        = (const float*)d_in[0];
    const float* start_w  = (const float*)d_in[1];
    const float* filter_w = (const float*)d_in[2];
    const float* gate_w   = (const float*)d_in[3];
    const float* res_w    = (const float*)d_in[4];
    const float* skip_w   = (const float*)d_in[5];
    const float* end1_w   = (const float*)d_in[6];
    const float* end1_b   = (const float*)d_in[7];
    const float* end2_w   = (const float*)d_in[8];
    const float* end2_b   = (const float*)d_in[9];
    float* out = (float*)d_out;
    float* ws  = (float*)d_ws;

    k1_fold <<<dim3(NL + 1, 2), 256, 0, stream>>>(x, start_w, filter_w,
                                                  gate_w, res_w, ws);
    k2_fused<<<8, 320, 0, stream>>>(skip_w, ws);
    k3b_end <<<dim3(4, 8), 256, 0, stream>>>(end1_w, end1_b, end2_w, end2_b,
                                             ws, out);
}